// Round 1
// baseline (112.218 us; speedup 1.0000x reference)
//
#include <hip/hip_runtime.h>

#define HOP 512
#define MAX_NHAR 128
#define N_MAX 4410
#define PI_D 3.14159265358979323846

// One block per frame, 128 threads = one harmonic per thread (2 waves).
// Direct harmonic DFT (the Bluestein CZT reduces to y[k] = sum_j xw[j] e^{-i th (k+1) j}).
// All phase-critical math in fp64: angle() branch cut at +/-pi makes fp32 phasor
// drift (~1e-4 rad) a guaranteed absmax failure across 131k outputs.
__global__ __launch_bounds__(128) void czt_direct_kernel(
    const float* __restrict__ x, const float* __restrict__ f0,
    float* __restrict__ out, int t, int F)
{
    __shared__ double sm[N_MAX];   // windowed frame, fp64 (35.3 KB -> 4 blocks/CU)
    const int frame = blockIdx.x;
    const int tid = threadIdx.x;

    double f0d = (double)f0[frame];
    if (f0d < 40.0) f0d = 40.0;                       // clip(f0, F0_MIN)
    const double inv = 44100.0 / f0d;
    // nhar = min(floor(SR/f0/2), 128); /2.0 is exact so inv*0.5 matches ref bit-for-bit
    const int nhar = (int)fmin(floor(inv * 0.5), 128.0);
    // winsize = round(SR/f0*REL_WIN/2)*2 ; *4/2 are exact pow2 scalings; rint = round-half-even
    int w = 2 * (int)rint(inv * 2.0);
    if (w > N_MAX) w = N_MAX;
    const double theta = (2.0 * PI_D * f0d) / 44100.0;

    // ---- stage Blackman-windowed samples into LDS (fp64) ----
    // win[j] = 0.42 - 0.5 cos(2pi j/w) + 0.08 cos(4pi j/w); cos(4pix) = 2cos^2(2pix)-1.
    // Rotating-phasor recurrence: 2 sincos per thread instead of 2 cos per sample.
    {
        const double invw = 1.0 / (double)w;
        double sa, ca, ss, cs;
        sincos((2.0 * PI_D) * ((double)tid * invw), &sa, &ca);
        sincos((2.0 * PI_D) * (128.0 * invw), &ss, &cs);
        double zr = ca, zi = sa;
        const int base = frame * HOP - (w >> 1);      // index into x (pad offset cancels)
        for (int j = tid; j < w; j += 128) {
            const int ix = base + j;
            const double val = (ix >= 0 && ix < t) ? (double)x[ix] : 0.0;
            const double c = zr;
            const double win = 0.42 - 0.5 * c + 0.08 * (2.0 * c * c - 1.0);
            sm[j] = val * win;
            const double nzr = zr * cs - zi * ss;     // advance by exp(i*2pi*128/w)
            zi = zr * ss + zi * cs;
            zr = nzr;
        }
    }
    __syncthreads();

    // ---- y[k] = sum_j sm[j] * e^{-i theta (k+1) j}, 4 independent phasor streams ----
    double s, c;
    sincos(theta * (double)(tid + 1), &s, &c);
    const double rr = c, ri = -s;                               // r   = e^{-i d}
    const double r2r = rr * rr - ri * ri, r2i = 2.0 * rr * ri;  // r^2
    const double r4r = r2r * r2r - r2i * r2i, r4i = 2.0 * r2r * r2i; // r^4
    const double r3r = r2r * rr - r2i * ri, r3i = r2r * ri + r2i * rr; // r^3

    double z0r = 1.0, z0i = 0.0;
    double z1r = rr,  z1i = ri;
    double z2r = r2r, z2i = r2i;
    double z3r = r3r, z3i = r3i;
    double a0r = 0.0, a0i = 0.0, a1r = 0.0, a1i = 0.0;
    double a2r = 0.0, a2i = 0.0, a3r = 0.0, a3i = 0.0;

    const int w4 = w & ~3;
    for (int j = 0; j < w4; j += 4) {
        const double s0 = sm[j], s1 = sm[j + 1], s2 = sm[j + 2], s3 = sm[j + 3];
        double tr;
        a0r = fma(s0, z0r, a0r); a0i = fma(s0, z0i, a0i);
        tr = z0r * r4r - z0i * r4i; z0i = z0r * r4i + z0i * r4r; z0r = tr;
        a1r = fma(s1, z1r, a1r); a1i = fma(s1, z1i, a1i);
        tr = z1r * r4r - z1i * r4i; z1i = z1r * r4i + z1i * r4r; z1r = tr;
        a2r = fma(s2, z2r, a2r); a2i = fma(s2, z2i, a2i);
        tr = z2r * r4r - z2i * r4i; z2i = z2r * r4i + z2i * r4r; z2r = tr;
        a3r = fma(s3, z3r, a3r); a3i = fma(s3, z3i, a3i);
        tr = z3r * r4r - z3i * r4i; z3i = z3r * r4i + z3i * r4r; z3r = tr;
    }
    if (w4 < w) {  // winsize is even -> remainder is exactly 2 samples
        const double s0 = sm[w4], s1 = sm[w4 + 1];
        a0r = fma(s0, z0r, a0r); a0i = fma(s0, z0i, a0i);
        a1r = fma(s1, z1r, a1r); a1i = fma(s1, z1i, a1i);
    }
    double yr = (a0r + a1r) + (a2r + a3r);
    double yi = (a0i + a1i) + (a2i + a3i);
    const double scale = 2.381 / (double)((w >> 1) + 1);
    yr *= scale; yi *= scale;

    float ampl = 0.0f, ph = 0.0f;
    if (tid < nhar) {
        ampl = (float)sqrt(yr * yr + yi * yi);
        ph   = (float)atan2(yi, yr);
    }
    out[tid * F + frame] = ampl;                    // ampl  (MAX_NHAR, F) row-major
    out[MAX_NHAR * F + tid * F + frame] = ph;       // phase (MAX_NHAR, F) row-major
}

extern "C" void kernel_launch(void* const* d_in, const int* in_sizes, int n_in,
                              void* d_out, int out_size, void* d_ws, size_t ws_size,
                              hipStream_t stream) {
    const float* x  = (const float*)d_in[0];
    const float* f0 = (const float*)d_in[1];
    float* out = (float*)d_out;
    const int t = in_sizes[0];   // 524288 samples
    const int F = in_sizes[1];   // 1024 frames
    czt_direct_kernel<<<F, 128, 0, stream>>>(x, f0, out, t, F);
}

// Round 2
// 101.707 us; speedup vs baseline: 1.1033x; 1.1033x over previous
//
#include <hip/hip_runtime.h>

#define HOP 512
#define MAX_NHAR 128
#define N_MAX 4410
#define SEGS 4
#define CHUNK_MAX 1104   // ceil(N_MAX/SEGS) rounded up to x4
#define PI_D 3.14159265358979323846

// ---------------------------------------------------------------------------
// Kernel 1: per-(frame,segment) partial harmonic DFT.
// y_k partial = sum_{j in [j0,j1)} xw[j] * e^{-i th (k+1) j}
// 4096 blocks x 128 thr: ~9KB LDS + 88 VGPR -> ~20 waves/CU resident with a
// queue behind them (dynamic load balance over variable winsize).
// fp64 throughout: fp32 phasor drift across ~1764 steps flips atan2 branch
// cuts (error 2*pi) with near-certainty over 131k outputs.
// ---------------------------------------------------------------------------
__global__ __launch_bounds__(128) void czt_partial_kernel(
    const float* __restrict__ x, const float* __restrict__ f0,
    double* __restrict__ ws, int t, int F)
{
    __shared__ double sm[CHUNK_MAX];
    const int frame = blockIdx.x >> 2;
    const int seg   = blockIdx.x & (SEGS - 1);
    const int tid   = threadIdx.x;

    double f0d = (double)f0[frame];
    if (f0d < 40.0) f0d = 40.0;
    const double inv = 44100.0 / f0d;
    int w = 2 * (int)rint(inv * 2.0);        // winsize (even), matches jnp.round
    if (w > N_MAX) w = N_MAX;
    const double theta = (2.0 * PI_D * f0d) / 44100.0;

    const int chunk = (((w + SEGS - 1) / SEGS) + 3) & ~3;   // x4 so mid-segments stay 4-aligned
    const int j0 = seg * chunk;
    const int j1 = (j0 + chunk < w) ? (j0 + chunk) : w;
    const int len = (j1 > j0) ? (j1 - j0) : 0;

    // ---- stage Blackman-windowed segment into LDS (rotating-phasor window) ----
    if (len > 0) {
        const double invw = 1.0 / (double)w;
        double sa, ca, ss, cs;
        sincos((2.0 * PI_D) * ((double)(j0 + tid) * invw), &sa, &ca);
        sincos((2.0 * PI_D) * (128.0 * invw), &ss, &cs);
        double zr = ca, zi = sa;
        const int base = frame * HOP - (w >> 1);
        for (int j = tid; j < len; j += 128) {
            const int ix = base + j0 + j;
            const double val = (ix >= 0 && ix < t) ? (double)x[ix] : 0.0;
            const double c = zr;
            const double win = 0.42 - 0.5 * c + 0.08 * (2.0 * c * c - 1.0);
            sm[j] = val * win;
            const double nzr = zr * cs - zi * ss;
            zi = zr * ss + zi * cs;
            zr = nzr;
        }
    }
    __syncthreads();

    // ---- partial sum for harmonic k=tid, 4 independent phasor streams ----
    double s, c;
    sincos(theta * (double)(tid + 1), &s, &c);
    const double rr = c, ri = -s;                                   // r = e^{-i th (k+1)}
    double pr, pi;                                                  // p = r^{j0}
    sincos(theta * (double)(tid + 1) * (double)j0, &s, &c);
    pr = c; pi = -s;
    const double r2r = rr * rr - ri * ri, r2i = 2.0 * rr * ri;
    const double r4r = r2r * r2r - r2i * r2i, r4i = 2.0 * r2r * r2i;

    double z0r = pr, z0i = pi;
    double z1r = pr * rr - pi * ri,   z1i = pr * ri + pi * rr;
    double z2r = pr * r2r - pi * r2i, z2i = pr * r2i + pi * r2r;
    double z3r = z2r * rr - z2i * ri, z3i = z2r * ri + z2i * rr;
    double a0r = 0.0, a0i = 0.0, a1r = 0.0, a1i = 0.0;
    double a2r = 0.0, a2i = 0.0, a3r = 0.0, a3i = 0.0;

    const int n4 = len & ~3;
    for (int j = 0; j < n4; j += 4) {
        const double s0 = sm[j], s1 = sm[j + 1], s2 = sm[j + 2], s3 = sm[j + 3];
        double tr;
        a0r = fma(s0, z0r, a0r); a0i = fma(s0, z0i, a0i);
        tr = z0r * r4r - z0i * r4i; z0i = z0r * r4i + z0i * r4r; z0r = tr;
        a1r = fma(s1, z1r, a1r); a1i = fma(s1, z1i, a1i);
        tr = z1r * r4r - z1i * r4i; z1i = z1r * r4i + z1i * r4r; z1r = tr;
        a2r = fma(s2, z2r, a2r); a2i = fma(s2, z2i, a2i);
        tr = z2r * r4r - z2i * r4i; z2i = z2r * r4i + z2i * r4r; z2r = tr;
        a3r = fma(s3, z3r, a3r); a3i = fma(s3, z3i, a3i);
        tr = z3r * r4r - z3i * r4i; z3i = z3r * r4i + z3i * r4r; z3r = tr;
    }
    const int rem = len - n4;   // 0..3 (even in practice)
    if (rem > 0) { const double sv = sm[n4];     a0r = fma(sv, z0r, a0r); a0i = fma(sv, z0i, a0i); }
    if (rem > 1) { const double sv = sm[n4 + 1]; a1r = fma(sv, z1r, a1r); a1i = fma(sv, z1i, a1i); }
    if (rem > 2) { const double sv = sm[n4 + 2]; a2r = fma(sv, z2r, a2r); a2i = fma(sv, z2i, a2i); }

    const double yr = (a0r + a1r) + (a2r + a3r);
    const double yi = (a0i + a1i) + (a2i + a3i);
    // ws layout: [frame][seg][k] complex double (empty segs write zeros: ws is re-poisoned)
    double* p = ws + ((size_t)(frame * SEGS + seg) * MAX_NHAR + tid) * 2;
    p[0] = yr; p[1] = yi;
}

// ---------------------------------------------------------------------------
// Kernel 2: reduce SEGS partials, scale, amplitude/phase, transpose-write.
// ---------------------------------------------------------------------------
__global__ __launch_bounds__(128) void czt_finalize_kernel(
    const float* __restrict__ f0, const double* __restrict__ ws,
    float* __restrict__ out, int F)
{
    const int frame = blockIdx.x;
    const int tid = threadIdx.x;

    double f0d = (double)f0[frame];
    if (f0d < 40.0) f0d = 40.0;
    const double inv = 44100.0 / f0d;
    const int nhar = (int)fmin(floor(inv * 0.5), 128.0);
    int w = 2 * (int)rint(inv * 2.0);
    if (w > N_MAX) w = N_MAX;

    double yr = 0.0, yi = 0.0;
    const double* p = ws + ((size_t)frame * SEGS * MAX_NHAR + tid) * 2;
    for (int sgm = 0; sgm < SEGS; ++sgm) {
        yr += p[0]; yi += p[1];
        p += (size_t)MAX_NHAR * 2;
    }
    const double scale = 2.381 / (double)((w >> 1) + 1);
    yr *= scale; yi *= scale;

    float ampl = 0.0f, ph = 0.0f;
    if (tid < nhar) {
        ampl = (float)sqrt(yr * yr + yi * yi);
        ph   = (float)atan2(yi, yr);
    }
    out[tid * F + frame] = ampl;
    out[MAX_NHAR * F + tid * F + frame] = ph;
}

// ---------------------------------------------------------------------------
// Fallback: original single-kernel direct DFT (used if ws_size is too small).
// ---------------------------------------------------------------------------
__global__ __launch_bounds__(128) void czt_direct_kernel(
    const float* __restrict__ x, const float* __restrict__ f0,
    float* __restrict__ out, int t, int F)
{
    __shared__ double sm[N_MAX];
    const int frame = blockIdx.x;
    const int tid = threadIdx.x;

    double f0d = (double)f0[frame];
    if (f0d < 40.0) f0d = 40.0;
    const double inv = 44100.0 / f0d;
    const int nhar = (int)fmin(floor(inv * 0.5), 128.0);
    int w = 2 * (int)rint(inv * 2.0);
    if (w > N_MAX) w = N_MAX;
    const double theta = (2.0 * PI_D * f0d) / 44100.0;

    {
        const double invw = 1.0 / (double)w;
        double sa, ca, ss, cs;
        sincos((2.0 * PI_D) * ((double)tid * invw), &sa, &ca);
        sincos((2.0 * PI_D) * (128.0 * invw), &ss, &cs);
        double zr = ca, zi = sa;
        const int base = frame * HOP - (w >> 1);
        for (int j = tid; j < w; j += 128) {
            const int ix = base + j;
            const double val = (ix >= 0 && ix < t) ? (double)x[ix] : 0.0;
            const double c = zr;
            const double win = 0.42 - 0.5 * c + 0.08 * (2.0 * c * c - 1.0);
            sm[j] = val * win;
            const double nzr = zr * cs - zi * ss;
            zi = zr * ss + zi * cs;
            zr = nzr;
        }
    }
    __syncthreads();

    double s, c;
    sincos(theta * (double)(tid + 1), &s, &c);
    const double rr = c, ri = -s;
    const double r2r = rr * rr - ri * ri, r2i = 2.0 * rr * ri;
    const double r4r = r2r * r2r - r2i * r2i, r4i = 2.0 * r2r * r2i;
    const double r3r = r2r * rr - r2i * ri, r3i = r2r * ri + r2i * rr;

    double z0r = 1.0, z0i = 0.0;
    double z1r = rr,  z1i = ri;
    double z2r = r2r, z2i = r2i;
    double z3r = r3r, z3i = r3i;
    double a0r = 0.0, a0i = 0.0, a1r = 0.0, a1i = 0.0;
    double a2r = 0.0, a2i = 0.0, a3r = 0.0, a3i = 0.0;

    const int w4 = w & ~3;
    for (int j = 0; j < w4; j += 4) {
        const double s0 = sm[j], s1 = sm[j + 1], s2 = sm[j + 2], s3 = sm[j + 3];
        double tr;
        a0r = fma(s0, z0r, a0r); a0i = fma(s0, z0i, a0i);
        tr = z0r * r4r - z0i * r4i; z0i = z0r * r4i + z0i * r4r; z0r = tr;
        a1r = fma(s1, z1r, a1r); a1i = fma(s1, z1i, a1i);
        tr = z1r * r4r - z1i * r4i; z1i = z1r * r4i + z1i * r4r; z1r = tr;
        a2r = fma(s2, z2r, a2r); a2i = fma(s2, z2i, a2i);
        tr = z2r * r4r - z2i * r4i; z2i = z2r * r4i + z2i * r4r; z2r = tr;
        a3r = fma(s3, z3r, a3r); a3i = fma(s3, z3i, a3i);
        tr = z3r * r4r - z3i * r4i; z3i = z3r * r4i + z3i * r4r; z3r = tr;
    }
    if (w4 < w) {
        const double s0 = sm[w4], s1 = sm[w4 + 1];
        a0r = fma(s0, z0r, a0r); a0i = fma(s0, z0i, a0i);
        a1r = fma(s1, z1r, a1r); a1i = fma(s1, z1i, a1i);
    }
    double yr = (a0r + a1r) + (a2r + a3r);
    double yi = (a0i + a1i) + (a2i + a3i);
    const double scale = 2.381 / (double)((w >> 1) + 1);
    yr *= scale; yi *= scale;

    float ampl = 0.0f, ph = 0.0f;
    if (tid < nhar) {
        ampl = (float)sqrt(yr * yr + yi * yi);
        ph   = (float)atan2(yi, yr);
    }
    out[tid * F + frame] = ampl;
    out[MAX_NHAR * F + tid * F + frame] = ph;
}

extern "C" void kernel_launch(void* const* d_in, const int* in_sizes, int n_in,
                              void* d_out, int out_size, void* d_ws, size_t ws_size,
                              hipStream_t stream) {
    const float* x  = (const float*)d_in[0];
    const float* f0 = (const float*)d_in[1];
    float* out = (float*)d_out;
    const int t = in_sizes[0];
    const int F = in_sizes[1];

    const size_t need = (size_t)F * SEGS * MAX_NHAR * 2 * sizeof(double);
    if (ws_size >= need) {
        double* ws = (double*)d_ws;
        czt_partial_kernel<<<F * SEGS, 128, 0, stream>>>(x, f0, ws, t, F);
        czt_finalize_kernel<<<F, 128, 0, stream>>>(f0, ws, out, F);
    } else {
        czt_direct_kernel<<<F, 128, 0, stream>>>(x, f0, out, t, F);
    }
}

// Round 3
// 82.651 us; speedup vs baseline: 1.3577x; 1.2306x over previous
//
#include <hip/hip_runtime.h>

#define HOP 512
#define MAX_NHAR 128
#define N_MAX 4410
#define CHUNK_MAX 1104          // worst case at SEGS=4
#define PI_D 3.14159265358979323846

// ---------------------------------------------------------------------------
// Shared frame-parameter computation (matches reference bit-for-bit; R1/R2
// achieved absmax 0.0 with this).
// ---------------------------------------------------------------------------
__device__ __forceinline__ void frame_params(double f0v, int& w, int& nhar, double& theta) {
    double f0d = f0v < 40.0 ? 40.0 : f0v;
    const double inv = 44100.0 / f0d;
    nhar = (int)fmin(floor(inv * 0.5), 128.0);
    w = 2 * (int)rint(inv * 2.0);
    if (w > N_MAX) w = N_MAX;
    theta = (2.0 * PI_D * f0d) / 44100.0;
}

__device__ __forceinline__ int chunk_of(int w, int segs) {
    return (((w + segs - 1) / segs) + 3) & ~3;
}

// ---------------------------------------------------------------------------
// Kernel P: table C[f][k] = cos(theta_f * (k+1)). Removes all harmonic
// sincos from the hot kernel. F blocks x 128 threads.
// ---------------------------------------------------------------------------
__global__ __launch_bounds__(128) void prep_kernel(
    const float* __restrict__ f0, double* __restrict__ ccos, int F)
{
    const int f = blockIdx.x, k = threadIdx.x;
    int w, nhar; double theta;
    frame_params((double)f0[f], w, nhar, theta);
    ccos[f * MAX_NHAR + k] = cos(theta * (double)(k + 1));
}

// ---------------------------------------------------------------------------
// Kernel G (hot): per (frame, segment) real Goertzel. 2 fp64 ops/sample/harmonic.
// Chain: s0 = fma(C, s1, x - s2) -> 8 cyc latency == 8 cyc fp64 issue -> pipe
// saturates at 1 wave/SIMD. Stores raw (s1, s2) per (f,seg,k).
// fp64 throughout: atan2 branch-cut at +/-pi makes fp32 drift a 2*pi absmax fail.
// ---------------------------------------------------------------------------
template <int SEGS>
__global__ __launch_bounds__(128) void goertzel_kernel(
    const float* __restrict__ x, const float* __restrict__ f0,
    const double* __restrict__ ccos, double2* __restrict__ parts,
    int t, int F)
{
    __shared__ double sm[CHUNK_MAX];
    const int frame = blockIdx.x / SEGS;
    const int seg   = blockIdx.x % SEGS;
    const int tid   = threadIdx.x;

    int w, nhar; double theta;
    frame_params((double)f0[frame], w, nhar, theta);

    const int chunk = chunk_of(w, SEGS);
    const int j0 = seg * chunk;
    int len = w - j0; if (len > chunk) len = chunk; if (len < 0) len = 0;

    // ---- stage Blackman-windowed samples (one fp64 cos per sample) ----
    {
        const double c2pi_invw = (2.0 * PI_D) / (double)w;
        const int base = frame * HOP - (w >> 1) + j0;
        for (int j = tid; j < len; j += 128) {
            const int ix = base + j;
            const double val = (ix >= 0 && ix < t) ? (double)x[ix] : 0.0;
            const double c1 = cos(c2pi_invw * (double)(j0 + j));
            // 0.42 - 0.5 c + 0.08 (2c^2 - 1) = 0.34 - 0.5 c + 0.16 c^2
            const double win = fma(0.16, c1 * c1, 0.34) - 0.5 * c1;
            sm[j] = val * win;
        }
    }
    __syncthreads();

    // ---- Goertzel for harmonic k = tid ----
    // Whole-wave skip when this wave's harmonics are all >= nhar (finalize
    // masks them to zero anyway): saves ~9% on high-f0 frames.
    const int kbase = tid & ~63;
    const int mylen = (kbase >= nhar) ? 0 : len;
    const double C = 2.0 * ccos[frame * MAX_NHAR + tid];
    double s1 = 0.0, s2 = 0.0;
    #pragma unroll 4
    for (int j = 0; j < mylen; ++j) {
        const double s0 = fma(C, s1, sm[j] - s2);
        s2 = s1; s1 = s0;
    }
    parts[(size_t)(frame * SEGS + seg) * MAX_NHAR + tid] = make_double2(s1, s2);
}

// ---------------------------------------------------------------------------
// Kernel F: combine SEGS partials with analytic rotations, scale, amp/phase.
// partial_y(seg) = P_seg * (s1 - e^{-iw} s2),  P_seg = e^{-iw (j0+len-1)}.
// Mid segs have len == chunk -> P advances by Q = e^{-iw*chunk} (recurrence);
// last seg uses e^{-iw (w-1)} directly.  3 fp64 sincos per lane, 2048 waves.
// ---------------------------------------------------------------------------
template <int SEGS>
__global__ __launch_bounds__(128) void finalize_kernel(
    const float* __restrict__ f0, const double2* __restrict__ parts,
    float* __restrict__ out, int F)
{
    const int frame = blockIdx.x;
    const int tid = threadIdx.x;

    int w, nhar; double theta;
    frame_params((double)f0[frame], w, nhar, theta);
    const int chunk = chunk_of(w, SEGS);
    const double omega = theta * (double)(tid + 1);

    double sw, cw; sincos(omega, &sw, &cw);                        // e^{-iw} = (cw, -sw)
    double sq, cq; sincos(omega * (double)chunk, &sq, &cq);        // Q = (cq, -sq)
    double sl, cl; sincos(omega * (double)(w - 1), &sl, &cl);      // last-seg phasor

    // R = e^{-iw (chunk-1)} = Q * e^{+iw}
    double Rr = cq * cw + sq * sw, Ri = cq * sw - sq * cw;
    double yr = 0.0, yi = 0.0;
    const double2* p = parts + (size_t)frame * SEGS * MAX_NHAR + tid;
    #pragma unroll
    for (int s = 0; s < SEGS; ++s) {
        const double2 v = p[(size_t)s * MAX_NHAR];
        const double tr = fma(-cw, v.y, v.x);       // s1 - cw*s2
        const double ti = sw * v.y;                 // + sw*s2
        const double Pr = (s == SEGS - 1) ? cl : Rr;
        const double Pi = (s == SEGS - 1) ? -sl : Ri;
        yr = fma(Pr, tr, fma(-Pi, ti, yr));
        yi = fma(Pr, ti, fma( Pi, tr, yi));
        const double nr = Rr * cq + Ri * sq;        // R *= Q
        Ri = Ri * cq - Rr * sq; Rr = nr;
    }
    const double scale = 2.381 / (double)((w >> 1) + 1);
    yr *= scale; yi *= scale;

    float ampl = 0.0f, ph = 0.0f;
    if (tid < nhar) {
        ampl = (float)sqrt(yr * yr + yi * yi);
        ph   = (float)atan2(yi, yr);
    }
    out[tid * F + frame] = ampl;
    out[MAX_NHAR * F + tid * F + frame] = ph;
}

// ---------------------------------------------------------------------------
// Fallback: single-kernel direct DFT (R1 version) if ws is too small.
// ---------------------------------------------------------------------------
__global__ __launch_bounds__(128) void czt_direct_kernel(
    const float* __restrict__ x, const float* __restrict__ f0,
    float* __restrict__ out, int t, int F)
{
    __shared__ double sm[N_MAX];
    const int frame = blockIdx.x;
    const int tid = threadIdx.x;
    int w, nhar; double theta;
    frame_params((double)f0[frame], w, nhar, theta);
    {
        const double invw = 1.0 / (double)w;
        double sa, ca, ss, cs;
        sincos((2.0 * PI_D) * ((double)tid * invw), &sa, &ca);
        sincos((2.0 * PI_D) * (128.0 * invw), &ss, &cs);
        double zr = ca, zi = sa;
        const int base = frame * HOP - (w >> 1);
        for (int j = tid; j < w; j += 128) {
            const int ix = base + j;
            const double val = (ix >= 0 && ix < t) ? (double)x[ix] : 0.0;
            const double c = zr;
            const double win = 0.42 - 0.5 * c + 0.08 * (2.0 * c * c - 1.0);
            sm[j] = val * win;
            const double nzr = zr * cs - zi * ss;
            zi = zr * ss + zi * cs;
            zr = nzr;
        }
    }
    __syncthreads();
    double s, c;
    sincos(theta * (double)(tid + 1), &s, &c);
    const double rr = c, ri = -s;
    const double r2r = rr * rr - ri * ri, r2i = 2.0 * rr * ri;
    const double r4r = r2r * r2r - r2i * r2i, r4i = 2.0 * r2r * r2i;
    const double r3r = r2r * rr - r2i * ri, r3i = r2r * ri + r2i * rr;
    double z0r = 1.0, z0i = 0.0, z1r = rr, z1i = ri;
    double z2r = r2r, z2i = r2i, z3r = r3r, z3i = r3i;
    double a0r = 0, a0i = 0, a1r = 0, a1i = 0, a2r = 0, a2i = 0, a3r = 0, a3i = 0;
    const int w4 = w & ~3;
    for (int j = 0; j < w4; j += 4) {
        const double s0 = sm[j], s1 = sm[j + 1], s2 = sm[j + 2], s3 = sm[j + 3];
        double tr;
        a0r = fma(s0, z0r, a0r); a0i = fma(s0, z0i, a0i);
        tr = z0r * r4r - z0i * r4i; z0i = z0r * r4i + z0i * r4r; z0r = tr;
        a1r = fma(s1, z1r, a1r); a1i = fma(s1, z1i, a1i);
        tr = z1r * r4r - z1i * r4i; z1i = z1r * r4i + z1i * r4r; z1r = tr;
        a2r = fma(s2, z2r, a2r); a2i = fma(s2, z2i, a2i);
        tr = z2r * r4r - z2i * r4i; z2i = z2r * r4i + z2i * r4r; z2r = tr;
        a3r = fma(s3, z3r, a3r); a3i = fma(s3, z3i, a3i);
        tr = z3r * r4r - z3i * r4i; z3i = z3r * r4i + z3i * r4r; z3r = tr;
    }
    if (w4 < w) {
        const double s0 = sm[w4], s1 = sm[w4 + 1];
        a0r = fma(s0, z0r, a0r); a0i = fma(s0, z0i, a0i);
        a1r = fma(s1, z1r, a1r); a1i = fma(s1, z1i, a1i);
    }
    double yr = (a0r + a1r) + (a2r + a3r);
    double yi = (a0i + a1i) + (a2i + a3i);
    const double scale = 2.381 / (double)((w >> 1) + 1);
    yr *= scale; yi *= scale;
    float ampl = 0.0f, ph = 0.0f;
    if (tid < nhar) {
        ampl = (float)sqrt(yr * yr + yi * yi);
        ph   = (float)atan2(yi, yr);
    }
    out[tid * F + frame] = ampl;
    out[MAX_NHAR * F + tid * F + frame] = ph;
}

extern "C" void kernel_launch(void* const* d_in, const int* in_sizes, int n_in,
                              void* d_out, int out_size, void* d_ws, size_t ws_size,
                              hipStream_t stream) {
    const float* x  = (const float*)d_in[0];
    const float* f0 = (const float*)d_in[1];
    float* out = (float*)d_out;
    const int t = in_sizes[0];
    const int F = in_sizes[1];

    const size_t table_bytes = (size_t)F * MAX_NHAR * sizeof(double);
    const size_t need8 = table_bytes + (size_t)F * 8 * MAX_NHAR * sizeof(double2);
    const size_t need4 = table_bytes + (size_t)F * 4 * MAX_NHAR * sizeof(double2);

    if (ws_size >= need8) {
        double* ccos = (double*)d_ws;
        double2* parts = (double2*)((char*)d_ws + table_bytes);
        prep_kernel<<<F, 128, 0, stream>>>(f0, ccos, F);
        goertzel_kernel<8><<<F * 8, 128, 0, stream>>>(x, f0, ccos, parts, t, F);
        finalize_kernel<8><<<F, 128, 0, stream>>>(f0, parts, out, F);
    } else if (ws_size >= need4) {
        double* ccos = (double*)d_ws;
        double2* parts = (double2*)((char*)d_ws + table_bytes);
        prep_kernel<<<F, 128, 0, stream>>>(f0, ccos, F);
        goertzel_kernel<4><<<F * 4, 128, 0, stream>>>(x, f0, ccos, parts, t, F);
        finalize_kernel<4><<<F, 128, 0, stream>>>(f0, parts, out, F);
    } else {
        czt_direct_kernel<<<F, 128, 0, stream>>>(x, f0, out, t, F);
    }
}